// Round 13
// baseline (116.231 us; speedup 1.0000x reference)
//
#include <hip/hip_runtime.h>

typedef unsigned int uint;
typedef unsigned short u16;
typedef unsigned char u8;
typedef unsigned long long u64;
typedef float f32x4 __attribute__((ext_vector_type(4)));

#define K_SEL   13107u
#define BATCH   256
#define UNITS   131072
#define HB      4096      // 12-bit first-stage bins
#define CAP     8192      // candidate capacity per row (expect ~2800)
#define NCHUNK  4
#define NRG     32        // row-groups in apply (8 rows each)
#define EQLDS   2048      // max eq-key elements handled in LDS
#define EQWIN   256       // max tie winners

#define MODE_ALL  0xFFFFFFFFu
#define MODE_SCAN 0xFFFFFFFEu

// ---------- workspace layout (bytes) ----------
// 0         boost   [131072] f32             524288
// 524288    ghist   [4][256][4096] u16      8388608  (fully rewritten)
// 8912896   candcnt [256][16] u32             16384  (zeroed by boost_kernel)
// 8929280   b1      [256] u32                  1024
// 8930304   prior   [256] u32                  1024
// 8931328   candkv  [256][CAP] u64         16777216  (key<<32 | idx)
// 25708544  cnt8    [32][131072] u8         4194304
// 29902848  fixdec  [131072] u32             524288  (zeroed by boost_kernel)
// total 30427136 (~29 MB)

__device__ __forceinline__ uint tokey(float f) {
    uint b = __float_as_uint(f);
    return b ^ ((uint)((int)b >> 31) | 0x80000000u);
}

__device__ __forceinline__ float4 nt_load4(const float4* p) {
    f32x4 v = __builtin_nontemporal_load((const f32x4*)p);
    return make_float4(v.x, v.y, v.z, v.w);
}

// Also zeroes candcnt + fixdec (no separate memset dispatch).
__global__ void boost_kernel(const float* __restrict__ duty, float* __restrict__ boost,
                             uint* __restrict__ candcnt, uint* __restrict__ fixdec) {
    int u = blockIdx.x * 256 + threadIdx.x;
    const float TARGET = (float)(13107.0 / 131072.0);
    float t = __fsub_rn(TARGET, duty[u]);
    boost[u] = (float)exp((double)t);   // correctly-rounded f32, matches np.exp
    fixdec[u] = 0u;
    if (u < BATCH * 16) candcnt[u] = 0u;
}

// Streaming histogram: per-(chunk,row) private 4096-bin u16 slab, NO global
// atomics, NO fences. 512 threads, 32KB LDS -> 4 blocks/CU, 32 waves/CU.
__global__ __launch_bounds__(512) void hist_kernel(const float* __restrict__ in,
                                                   const float* __restrict__ boost,
                                                   u16* __restrict__ ghist) {
    __shared__ uint lh[2][HB];
    const int row = blockIdx.y;
    uint* h = lh[(threadIdx.x >> 7) & 1];
    for (int i = threadIdx.x; i < 2 * HB; i += 512) ((uint*)lh)[i] = 0u;
    __syncthreads();

    const float4* inp = (const float4*)(in + (size_t)row * UNITS) + (size_t)blockIdx.x * 8192;
    const float4* bst = (const float4*)boost + (size_t)blockIdx.x * 8192;
    for (int i = 0; i < 16; i++) {
        int idx = i * 512 + threadIdx.x;
        float4 a = inp[idx];
        float4 b = bst[idx];
        atomicAdd(&h[tokey(a.x * b.x) >> 20], 1u);
        atomicAdd(&h[tokey(a.y * b.y) >> 20], 1u);
        atomicAdd(&h[tokey(a.z * b.z) >> 20], 1u);
        atomicAdd(&h[tokey(a.w * b.w) >> 20], 1u);
    }
    __syncthreads();
    u16* gh = ghist + ((size_t)blockIdx.x * BATCH + row) * HB;
    for (int i = threadIdx.x; i < HB; i += 512)
        gh[i] = (u16)(lh[0][i] + lh[1][i]);   // block total <= 32768, fits u16
}

// Per row: sum 4 u16 slabs, find crossing bin b1 and prior (count above).
__global__ __launch_bounds__(512) void scan_kernel(const u16* __restrict__ ghist,
                                                   uint* __restrict__ b1_a,
                                                   uint* __restrict__ prior_a) {
    __shared__ uint ts[512];
    __shared__ uint bc[2];
    const int row = blockIdx.x;
    const int tid = threadIdx.x;

    const int b0 = tid * 8;
    uint binsum[8];
    uint segsum = 0;
    for (int i = 0; i < 8; i++) {
        uint s = 0;
        for (int c = 0; c < NCHUNK; c++)
            s += (uint)ghist[((size_t)c * BATCH + row) * HB + b0 + i];
        binsum[i] = s;
        segsum += s;
    }
    ts[tid] = segsum;
    __syncthreads();
    for (int off = 1; off < 512; off <<= 1) {
        uint v = (tid + off < 512) ? ts[tid + off] : 0u;
        __syncthreads();
        ts[tid] += v;
        __syncthreads();
    }
    uint cum = ts[tid] - segsum;   // strictly-greater count above my segment
    for (int i = 7; i >= 0; i--) {
        uint hb = binsum[i];
        uint c2 = cum + hb;
        if (cum < K_SEL && c2 >= K_SEL) { bc[0] = (uint)(b0 + i); bc[1] = cum; }
        cum = c2;
    }
    __syncthreads();
    if (tid == 0) { b1_a[row] = bc[0]; prior_a[row] = bc[1]; }
}

// Streaming apply: 512 threads x 8 elements (two unit-stride float4 runs ->
// coalesced + 2x MLP); 8 rows/block (unroll 2 -> two independent row chains
// in flight); NT loads (last reader of in) + NT stores (out never re-read).
__global__ __launch_bounds__(512) void apply_kernel(const float* __restrict__ in,
                                                    const float* __restrict__ boost,
                                                    const uint* __restrict__ b1_a,
                                                    float* __restrict__ out,
                                                    u8* __restrict__ cnt8,
                                                    uint* __restrict__ candcnt,
                                                    u64* __restrict__ candkv) {
    __shared__ uint s_b1[8];
    const int r0 = blockIdx.y * 8;
    if (threadIdx.x < 8) s_b1[threadIdx.x] = b1_a[r0 + threadIdx.x];
    __syncthreads();

    const int lane = threadIdx.x & 63;
    const u64 ltmask = ((u64)1 << lane) - 1;
    const int c0 = blockIdx.x * 1024 + threadIdx.x;   // float4 index, run A
    const int c1 = c0 + 512;                          // float4 index, run B
    const float4 bst0 = ((const float4*)boost)[c0];
    const float4 bst1 = ((const float4*)boost)[c1];
    const uint u0a = (uint)c0 * 4u;
    const uint u0b = (uint)c1 * 4u;
    const float bb[8] = {bst0.x, bst0.y, bst0.z, bst0.w, bst1.x, bst1.y, bst1.z, bst1.w};
    uint cnt[8] = {0u, 0u, 0u, 0u, 0u, 0u, 0u, 0u};

    #pragma unroll 2
    for (int r = 0; r < 8; r++) {
        const int row = r0 + r;
        const float4* inr = (const float4*)(in + (size_t)row * UNITS);
        const float4 v0 = nt_load4(inr + c0);
        const float4 v1 = nt_load4(inr + c1);
        const uint b1 = s_b1[r];
        const float vv[8] = {v0.x, v0.y, v0.z, v0.w, v1.x, v1.y, v1.z, v1.w};
        float o[8];
        uint k[8];
        bool f[8];
        #pragma unroll
        for (int c = 0; c < 8; c++) {
            k[c] = tokey(vv[c] * bb[c]);
            const uint kb = k[c] >> 20;
            const bool keep = kb >= b1;       // provisional win (losers fixed later)
            o[c] = keep ? vv[c] : 0.0f;
            cnt[c] += keep ? 1u : 0u;
            f[c] = (kb == b1);
        }
        f32x4 ovA = {o[0], o[1], o[2], o[3]};
        f32x4 ovB = {o[4], o[5], o[6], o[7]};
        float* outr = out + (size_t)row * UNITS;
        __builtin_nontemporal_store(ovA, (f32x4*)outr + c0);
        __builtin_nontemporal_store(ovB, (f32x4*)outr + c1);

        u64 bal[8];
        uint wtot = 0;
        #pragma unroll
        for (int c = 0; c < 8; c++) { bal[c] = __ballot(f[c]); wtot += (uint)__popcll(bal[c]); }
        if (wtot) {   // wave-uniform
            uint sbase = 0;
            if (lane == 0) sbase = atomicAdd(&candcnt[row * 16], wtot);
            sbase = (uint)__shfl((int)sbase, 0);
            uint cum = 0;
            #pragma unroll
            for (int c = 0; c < 8; c++) {
                if (f[c]) {
                    uint pos = sbase + cum + (uint)__popcll(bal[c] & ltmask);
                    if (pos < CAP) {
                        const uint u = (c < 4) ? (u0a + (uint)c) : (u0b + (uint)(c - 4));
                        candkv[(size_t)row * CAP + pos] = ((u64)k[c] << 32) | (u64)u;
                    }
                }
                cum += (uint)__popcll(bal[c]);
            }
        }
    }
    u8* cslab = cnt8 + (size_t)blockIdx.y * UNITS;
    ((uchar4*)cslab)[c0] = make_uchar4((u8)cnt[0], (u8)cnt[1], (u8)cnt[2], (u8)cnt[3]);
    ((uchar4*)cslab)[c1] = make_uchar4((u8)cnt[4], (u8)cnt[5], (u8)cnt[6], (u8)cnt[7]);
}

// 1024-bin suffix-scan crossing finder, 512 threads (2 bins each).
__device__ __forceinline__ void find_cross_1024_t512(const uint* __restrict__ h, uint* ts,
                                                     uint need, uint* out3, int tid) {
    uint binsum[2];
    uint segsum = 0;
    const int b0 = tid * 2;
    for (int i = 0; i < 2; i++) { binsum[i] = h[b0 + i]; segsum += binsum[i]; }
    ts[tid] = segsum;
    __syncthreads();
    for (int off = 1; off < 512; off <<= 1) {
        uint v = (tid + off < 512) ? ts[tid + off] : 0u;
        __syncthreads();
        ts[tid] += v;
        __syncthreads();
    }
    uint cum = ts[tid] - segsum;
    for (int i = 1; i >= 0; i--) {
        uint hb = binsum[i];
        uint c2 = cum + hb;
        if (cum < need && c2 >= need) { out3[0] = (uint)(b0 + i); out3[1] = cum; out3[2] = hb; }
        cum = c2;
    }
    __syncthreads();
}

// Fused per-row finisher: exact 32-bit threshold via 20-bit LDS radix select,
// lowest-index tie-break, then zero losing candidates + record decrements.
__global__ __launch_bounds__(512) void fix_kernel(const uint* __restrict__ candcnt,
                                                  const u64* __restrict__ candkv,
                                                  const uint* __restrict__ prior_a,
                                                  float* __restrict__ out,
                                                  uint* __restrict__ fixdec) {
    __shared__ uint kbuf[CAP];
    __shared__ uint ibuf[CAP];
    __shared__ uint h1[1024];
    __shared__ uint ts[512];
    __shared__ uint sh[6];
    __shared__ uint eqlist[EQLDS];
    __shared__ uint wlist[EQWIN];
    __shared__ uint ecnt_s, wn_s;
    const int row = blockIdx.x;
    const int tid = threadIdx.x;
    const uint n = min(candcnt[row * 16], (uint)CAP);
    const uint needbin = K_SEL - prior_a[row];
    const u64* kv = candkv + (size_t)row * CAP;

    if (needbin >= n) return;   // every candidate wins; no losers to fix

    for (uint i = tid; i < n; i += 512) {
        u64 x = __builtin_nontemporal_load(kv + i);
        kbuf[i] = (uint)(x >> 32);
        ibuf[i] = (uint)x;
    }
    // round 1: bits 19:10
    for (int i = tid; i < 1024; i += 512) h1[i] = 0u;
    __syncthreads();
    for (uint i = tid; i < n; i += 512) atomicAdd(&h1[(kbuf[i] >> 10) & 1023u], 1u);
    __syncthreads();
    find_cross_1024_t512(h1, ts, needbin, sh, tid);
    const uint b2 = sh[0];
    const uint need2 = needbin - sh[1];
    __syncthreads();
    // round 2: bits 9:0 within crossing bin
    for (int i = tid; i < 1024; i += 512) h1[i] = 0u;
    __syncthreads();
    for (uint i = tid; i < n; i += 512)
        if (((kbuf[i] >> 10) & 1023u) == b2) atomicAdd(&h1[kbuf[i] & 1023u], 1u);
    __syncthreads();
    find_cross_1024_t512(h1, ts, need2, sh + 3, tid);
    const uint b3 = sh[3];
    const uint tk = (kbuf[0] & 0xFFF00000u) | (b2 << 10) | b3;   // shared 12-bit prefix
    const uint nd_eq = need2 - sh[4];
    const uint eqc   = sh[5];

    uint mode;
    if (eqc == nd_eq) {
        mode = MODE_ALL;
    } else if (eqc <= (uint)EQLDS && nd_eq <= (uint)EQWIN) {
        if (tid == 0) { ecnt_s = 0u; wn_s = 0u; }
        __syncthreads();
        for (uint i = tid; i < n; i += 512)
            if (kbuf[i] == tk) { uint p = atomicAdd(&ecnt_s, 1u); eqlist[p] = ibuf[i]; }
        __syncthreads();
        const uint ec = ecnt_s;
        for (uint t = tid; t < ec; t += 512) {
            const uint my = eqlist[t];
            uint rank = 0;
            for (uint j = 0; j < ec; j++) rank += (eqlist[j] < my) ? 1u : 0u;
            if (rank < nd_eq) {                 // lowest-index-first winners
                uint p = atomicAdd(&wn_s, 1u);
                wlist[p] = my;
            }
        }
        __syncthreads();
        mode = wn_s;                             // == nd_eq
    } else {
        mode = MODE_SCAN;                        // bulletproof fallback
        __syncthreads();
    }

    // zero losers, record their decrements (uint arithmetic stays exact)
    for (uint i = tid; i < n; i += 512) {
        const uint k = kbuf[i];
        bool win;
        if (k > tk) {
            win = true;
        } else if (k < tk) {
            win = false;
        } else if (mode == MODE_ALL) {
            win = true;
        } else if (mode == MODE_SCAN) {
            const uint my = ibuf[i];
            uint rank = 0;
            for (uint j = 0; j < n; j++)
                if (kbuf[j] == tk && ibuf[j] < my) rank++;
            win = rank < nd_eq;
        } else {
            const uint my = ibuf[i];
            win = false;
            for (uint j = 0; j < mode; j++)
                if (wlist[j] == my) { win = true; break; }
        }
        if (!win) {
            const uint idx = ibuf[i];
            out[(size_t)row * UNITS + idx] = 0.0f;
            atomicAdd(&fixdec[idx], 1u);
        }
    }
}

// Per 4 columns: sum 32 u8 slabs via packed u16-lane adds, subtract fixdec.
__global__ __launch_bounds__(512) void duty_kernel(const float* __restrict__ duty,
                                                   const u8* __restrict__ cnt8,
                                                   const uint* __restrict__ fixdec,
                                                   float* __restrict__ out_duty) {
    const int w = blockIdx.x * 512 + threadIdx.x;   // word index: 4 columns
    const uint* cw = (const uint*)cnt8;
    uint even = 0, odd = 0;
    #pragma unroll
    for (int s = 0; s < NRG; s++) {
        uint x = __builtin_nontemporal_load(cw + (size_t)s * (UNITS / 4) + w);
        even += x & 0x00FF00FFu;          // byte lanes 0,2 in u16 sub-lanes
        odd  += (x >> 8) & 0x00FF00FFu;   // byte lanes 1,3
    }
    const uint4 fd = ((const uint4*)fixdec)[w];
    const float4 dv = ((const float4*)duty)[w];
    const uint c[4] = {(even & 0xFFFFu) - fd.x, (odd & 0xFFFFu) - fd.y,
                       (even >> 16) - fd.z,     (odd >> 16) - fd.w};
    const float din[4] = {dv.x, dv.y, dv.z, dv.w};
    const float C1 = (float)(1.0 - 1.0 / 1000.0);
    const float C2 = (float)(1.0 / 1000.0);
    float o[4];
    #pragma unroll
    for (int j = 0; j < 4; j++) {
        float cur = (float)c[j] * (1.0f / 256.0f);   // exact
        o[j] = __fadd_rn(__fmul_rn(C1, din[j]), __fmul_rn(C2, cur));
    }
    f32x4 ov = {o[0], o[1], o[2], o[3]};
    *((f32x4*)out_duty + w) = ov;
}

extern "C" void kernel_launch(void* const* d_in, const int* in_sizes, int n_in,
                              void* d_out, int out_size, void* d_ws, size_t ws_size,
                              hipStream_t stream) {
    const float* inputs = (const float*)d_in[0];
    const float* duty   = (const float*)d_in[1];
    float* out      = (float*)d_out;
    float* out_duty = out + (size_t)BATCH * UNITS;

    char* ws = (char*)d_ws;
    float* boost  = (float*)(ws + 0);
    u16*  ghist   = (u16*)(ws + 524288);
    uint* candcnt = (uint*)(ws + 8912896);
    uint* b1_a    = (uint*)(ws + 8929280);
    uint* prior_a = (uint*)(ws + 8930304);
    u64*  candkv  = (u64*)(ws + 8931328);
    u8*   cnt8    = (u8*)(ws + 25708544);
    uint* fixdec  = (uint*)(ws + 29902848);

    boost_kernel<<<UNITS / 256, 256, 0, stream>>>(duty, boost, candcnt, fixdec);

    hist_kernel<<<dim3(NCHUNK, BATCH), 512, 0, stream>>>(inputs, boost, ghist);

    scan_kernel<<<BATCH, 512, 0, stream>>>(ghist, b1_a, prior_a);

    apply_kernel<<<dim3(UNITS / 4096, NRG), 512, 0, stream>>>(inputs, boost, b1_a, out,
                                                              cnt8, candcnt, candkv);

    fix_kernel<<<BATCH, 512, 0, stream>>>(candcnt, candkv, prior_a, out, fixdec);

    duty_kernel<<<UNITS / 2048, 512, 0, stream>>>(duty, cnt8, fixdec, out_duty);
}

// Round 14
// 105.603 us; speedup vs baseline: 1.1006x; 1.1006x over previous
//
#include <hip/hip_runtime.h>

typedef unsigned int uint;
typedef unsigned short u16;
typedef unsigned char u8;
typedef unsigned long long u64;
typedef float f32x4 __attribute__((ext_vector_type(4)));

#define K_SEL   13107u
#define BATCH   256
#define UNITS   131072
#define HB      4096      // 12-bit first-stage bins
#define CAP     8192      // candidate capacity per row (expect ~2800)
#define NCHUNK  4
#define NRG     32        // row-groups in apply (8 rows each)
#define EQLDS   2048      // max eq-key elements handled in LDS
#define EQWIN   256       // max tie winners

#define MODE_ALL  0xFFFFFFFFu
#define MODE_SCAN 0xFFFFFFFEu

// ---------- workspace layout (bytes) ----------
// 0         boost   [131072] f32             524288
// 524288    ghist   [4][256][4096] u16      8388608  (fully rewritten)
// 8912896   candcnt [256][16] u32             16384  (zeroed by boost_kernel)
// 8929280   b1      [256] u32                  1024
// 8930304   prior   [256] u32                  1024
// 8931328   candkv  [256][CAP] u64         16777216  (key<<32 | idx)
// 25708544  cnt8    [32][131072] u8         4194304
// 29902848  fixdec  [131072] u32             524288  (zeroed by boost_kernel)
// total 30427136 (~29 MB)

__device__ __forceinline__ uint tokey(float f) {
    uint b = __float_as_uint(f);
    return b ^ ((uint)((int)b >> 31) | 0x80000000u);
}

// Also zeroes candcnt + fixdec (no separate memset dispatch).
__global__ void boost_kernel(const float* __restrict__ duty, float* __restrict__ boost,
                             uint* __restrict__ candcnt, uint* __restrict__ fixdec) {
    int u = blockIdx.x * 256 + threadIdx.x;
    const float TARGET = (float)(13107.0 / 131072.0);
    float t = __fsub_rn(TARGET, duty[u]);
    boost[u] = (float)exp((double)t);   // correctly-rounded f32, matches np.exp
    fixdec[u] = 0u;
    if (u < BATCH * 16) candcnt[u] = 0u;
}

// Streaming histogram: per-(chunk,row) private 4096-bin u16 slab, NO global
// atomics, NO fences. 512 threads, 32KB LDS -> 4 blocks/CU, 32 waves/CU.
__global__ __launch_bounds__(512) void hist_kernel(const float* __restrict__ in,
                                                   const float* __restrict__ boost,
                                                   u16* __restrict__ ghist) {
    __shared__ uint lh[2][HB];
    const int row = blockIdx.y;
    uint* h = lh[(threadIdx.x >> 7) & 1];
    for (int i = threadIdx.x; i < 2 * HB; i += 512) ((uint*)lh)[i] = 0u;
    __syncthreads();

    const float4* inp = (const float4*)(in + (size_t)row * UNITS) + (size_t)blockIdx.x * 8192;
    const float4* bst = (const float4*)boost + (size_t)blockIdx.x * 8192;
    for (int i = 0; i < 16; i++) {
        int idx = i * 512 + threadIdx.x;
        float4 a = inp[idx];
        float4 b = bst[idx];
        atomicAdd(&h[tokey(a.x * b.x) >> 20], 1u);
        atomicAdd(&h[tokey(a.y * b.y) >> 20], 1u);
        atomicAdd(&h[tokey(a.z * b.z) >> 20], 1u);
        atomicAdd(&h[tokey(a.w * b.w) >> 20], 1u);
    }
    __syncthreads();
    u16* gh = ghist + ((size_t)blockIdx.x * BATCH + row) * HB;
    for (int i = threadIdx.x; i < HB; i += 512)
        gh[i] = (u16)(lh[0][i] + lh[1][i]);   // block total <= 32768, fits u16
}

// Per row: sum 4 u16 slabs, find crossing bin b1 and prior (count above).
__global__ __launch_bounds__(512) void scan_kernel(const u16* __restrict__ ghist,
                                                   uint* __restrict__ b1_a,
                                                   uint* __restrict__ prior_a) {
    __shared__ uint ts[512];
    __shared__ uint bc[2];
    const int row = blockIdx.x;
    const int tid = threadIdx.x;

    const int b0 = tid * 8;
    uint binsum[8];
    uint segsum = 0;
    for (int i = 0; i < 8; i++) {
        uint s = 0;
        for (int c = 0; c < NCHUNK; c++)
            s += (uint)ghist[((size_t)c * BATCH + row) * HB + b0 + i];
        binsum[i] = s;
        segsum += s;
    }
    ts[tid] = segsum;
    __syncthreads();
    for (int off = 1; off < 512; off <<= 1) {
        uint v = (tid + off < 512) ? ts[tid + off] : 0u;
        __syncthreads();
        ts[tid] += v;
        __syncthreads();
    }
    uint cum = ts[tid] - segsum;   // strictly-greater count above my segment
    for (int i = 7; i >= 0; i--) {
        uint hb = binsum[i];
        uint c2 = cum + hb;
        if (cum < K_SEL && c2 >= K_SEL) { bc[0] = (uint)(b0 + i); bc[1] = cum; }
        cum = c2;
    }
    __syncthreads();
    if (tid == 0) { b1_a[row] = bc[0]; prior_a[row] = bc[1]; }
}

// Streaming apply: 512 threads x 8 elements (two unit-stride float4 runs ->
// coalesced + 2x MLP); 8 rows/block, unroll 2 -> two independent row chains.
// Regular loads (L3 is warm from hist); NT stores (out never re-read).
__global__ __launch_bounds__(512) void apply_kernel(const float* __restrict__ in,
                                                    const float* __restrict__ boost,
                                                    const uint* __restrict__ b1_a,
                                                    float* __restrict__ out,
                                                    u8* __restrict__ cnt8,
                                                    uint* __restrict__ candcnt,
                                                    u64* __restrict__ candkv) {
    __shared__ uint s_b1[8];
    const int r0 = blockIdx.y * 8;
    if (threadIdx.x < 8) s_b1[threadIdx.x] = b1_a[r0 + threadIdx.x];
    __syncthreads();

    const int lane = threadIdx.x & 63;
    const u64 ltmask = ((u64)1 << lane) - 1;
    const int c0 = blockIdx.x * 1024 + threadIdx.x;   // float4 index, run A
    const int c1 = c0 + 512;                          // float4 index, run B
    const float4 bst0 = ((const float4*)boost)[c0];
    const float4 bst1 = ((const float4*)boost)[c1];
    const uint u0a = (uint)c0 * 4u;
    const uint u0b = (uint)c1 * 4u;
    const float bb[8] = {bst0.x, bst0.y, bst0.z, bst0.w, bst1.x, bst1.y, bst1.z, bst1.w};
    uint cnt[8] = {0u, 0u, 0u, 0u, 0u, 0u, 0u, 0u};

    #pragma unroll 2
    for (int r = 0; r < 8; r++) {
        const int row = r0 + r;
        const float4* inr = (const float4*)(in + (size_t)row * UNITS);
        const float4 v0 = inr[c0];
        const float4 v1 = inr[c1];
        const uint b1 = s_b1[r];
        const float vv[8] = {v0.x, v0.y, v0.z, v0.w, v1.x, v1.y, v1.z, v1.w};
        float o[8];
        uint k[8];
        bool f[8];
        #pragma unroll
        for (int c = 0; c < 8; c++) {
            k[c] = tokey(vv[c] * bb[c]);
            const uint kb = k[c] >> 20;
            const bool keep = kb >= b1;       // provisional win (losers fixed later)
            o[c] = keep ? vv[c] : 0.0f;
            cnt[c] += keep ? 1u : 0u;
            f[c] = (kb == b1);
        }
        f32x4 ovA = {o[0], o[1], o[2], o[3]};
        f32x4 ovB = {o[4], o[5], o[6], o[7]};
        float* outr = out + (size_t)row * UNITS;
        __builtin_nontemporal_store(ovA, (f32x4*)outr + c0);
        __builtin_nontemporal_store(ovB, (f32x4*)outr + c1);

        u64 bal[8];
        uint wtot = 0;
        #pragma unroll
        for (int c = 0; c < 8; c++) { bal[c] = __ballot(f[c]); wtot += (uint)__popcll(bal[c]); }
        if (wtot) {   // wave-uniform
            uint sbase = 0;
            if (lane == 0) sbase = atomicAdd(&candcnt[row * 16], wtot);
            sbase = (uint)__shfl((int)sbase, 0);
            uint cum = 0;
            #pragma unroll
            for (int c = 0; c < 8; c++) {
                if (f[c]) {
                    uint pos = sbase + cum + (uint)__popcll(bal[c] & ltmask);
                    if (pos < CAP) {
                        const uint u = (c < 4) ? (u0a + (uint)c) : (u0b + (uint)(c - 4));
                        candkv[(size_t)row * CAP + pos] = ((u64)k[c] << 32) | (u64)u;
                    }
                }
                cum += (uint)__popcll(bal[c]);
            }
        }
    }
    u8* cslab = cnt8 + (size_t)blockIdx.y * UNITS;
    ((uchar4*)cslab)[c0] = make_uchar4((u8)cnt[0], (u8)cnt[1], (u8)cnt[2], (u8)cnt[3]);
    ((uchar4*)cslab)[c1] = make_uchar4((u8)cnt[4], (u8)cnt[5], (u8)cnt[6], (u8)cnt[7]);
}

// 1024-bin suffix-scan crossing finder, 512 threads (2 bins each).
__device__ __forceinline__ void find_cross_1024_t512(const uint* __restrict__ h, uint* ts,
                                                     uint need, uint* out3, int tid) {
    uint binsum[2];
    uint segsum = 0;
    const int b0 = tid * 2;
    for (int i = 0; i < 2; i++) { binsum[i] = h[b0 + i]; segsum += binsum[i]; }
    ts[tid] = segsum;
    __syncthreads();
    for (int off = 1; off < 512; off <<= 1) {
        uint v = (tid + off < 512) ? ts[tid + off] : 0u;
        __syncthreads();
        ts[tid] += v;
        __syncthreads();
    }
    uint cum = ts[tid] - segsum;
    for (int i = 1; i >= 0; i--) {
        uint hb = binsum[i];
        uint c2 = cum + hb;
        if (cum < need && c2 >= need) { out3[0] = (uint)(b0 + i); out3[1] = cum; out3[2] = hb; }
        cum = c2;
    }
    __syncthreads();
}

// Fused per-row finisher: exact 32-bit threshold via 20-bit LDS radix select,
// lowest-index tie-break, then zero losing candidates + record decrements.
__global__ __launch_bounds__(512) void fix_kernel(const uint* __restrict__ candcnt,
                                                  const u64* __restrict__ candkv,
                                                  const uint* __restrict__ prior_a,
                                                  float* __restrict__ out,
                                                  uint* __restrict__ fixdec) {
    __shared__ uint kbuf[CAP];
    __shared__ uint ibuf[CAP];
    __shared__ uint h1[1024];
    __shared__ uint ts[512];
    __shared__ uint sh[6];
    __shared__ uint eqlist[EQLDS];
    __shared__ uint wlist[EQWIN];
    __shared__ uint ecnt_s, wn_s;
    const int row = blockIdx.x;
    const int tid = threadIdx.x;
    const uint n = min(candcnt[row * 16], (uint)CAP);
    const uint needbin = K_SEL - prior_a[row];
    const u64* kv = candkv + (size_t)row * CAP;

    if (needbin >= n) return;   // every candidate wins; no losers to fix

    for (uint i = tid; i < n; i += 512) {
        u64 x = kv[i];
        kbuf[i] = (uint)(x >> 32);
        ibuf[i] = (uint)x;
    }
    // round 1: bits 19:10
    for (int i = tid; i < 1024; i += 512) h1[i] = 0u;
    __syncthreads();
    for (uint i = tid; i < n; i += 512) atomicAdd(&h1[(kbuf[i] >> 10) & 1023u], 1u);
    __syncthreads();
    find_cross_1024_t512(h1, ts, needbin, sh, tid);
    const uint b2 = sh[0];
    const uint need2 = needbin - sh[1];
    __syncthreads();
    // round 2: bits 9:0 within crossing bin
    for (int i = tid; i < 1024; i += 512) h1[i] = 0u;
    __syncthreads();
    for (uint i = tid; i < n; i += 512)
        if (((kbuf[i] >> 10) & 1023u) == b2) atomicAdd(&h1[kbuf[i] & 1023u], 1u);
    __syncthreads();
    find_cross_1024_t512(h1, ts, need2, sh + 3, tid);
    const uint b3 = sh[3];
    const uint tk = (kbuf[0] & 0xFFF00000u) | (b2 << 10) | b3;   // shared 12-bit prefix
    const uint nd_eq = need2 - sh[4];
    const uint eqc   = sh[5];

    uint mode;
    if (eqc == nd_eq) {
        mode = MODE_ALL;
    } else if (eqc <= (uint)EQLDS && nd_eq <= (uint)EQWIN) {
        if (tid == 0) { ecnt_s = 0u; wn_s = 0u; }
        __syncthreads();
        for (uint i = tid; i < n; i += 512)
            if (kbuf[i] == tk) { uint p = atomicAdd(&ecnt_s, 1u); eqlist[p] = ibuf[i]; }
        __syncthreads();
        const uint ec = ecnt_s;
        for (uint t = tid; t < ec; t += 512) {
            const uint my = eqlist[t];
            uint rank = 0;
            for (uint j = 0; j < ec; j++) rank += (eqlist[j] < my) ? 1u : 0u;
            if (rank < nd_eq) {                 // lowest-index-first winners
                uint p = atomicAdd(&wn_s, 1u);
                wlist[p] = my;
            }
        }
        __syncthreads();
        mode = wn_s;                             // == nd_eq
    } else {
        mode = MODE_SCAN;                        // bulletproof fallback
        __syncthreads();
    }

    // zero losers, record their decrements (uint arithmetic stays exact)
    for (uint i = tid; i < n; i += 512) {
        const uint k = kbuf[i];
        bool win;
        if (k > tk) {
            win = true;
        } else if (k < tk) {
            win = false;
        } else if (mode == MODE_ALL) {
            win = true;
        } else if (mode == MODE_SCAN) {
            const uint my = ibuf[i];
            uint rank = 0;
            for (uint j = 0; j < n; j++)
                if (kbuf[j] == tk && ibuf[j] < my) rank++;
            win = rank < nd_eq;
        } else {
            const uint my = ibuf[i];
            win = false;
            for (uint j = 0; j < mode; j++)
                if (wlist[j] == my) { win = true; break; }
        }
        if (!win) {
            const uint idx = ibuf[i];
            out[(size_t)row * UNITS + idx] = 0.0f;
            atomicAdd(&fixdec[idx], 1u);
        }
    }
}

// Per 4 columns: sum 32 u8 slabs via packed u16-lane adds, subtract fixdec.
__global__ __launch_bounds__(512) void duty_kernel(const float* __restrict__ duty,
                                                   const u8* __restrict__ cnt8,
                                                   const uint* __restrict__ fixdec,
                                                   float* __restrict__ out_duty) {
    const int w = blockIdx.x * 512 + threadIdx.x;   // word index: 4 columns
    const uint* cw = (const uint*)cnt8;
    uint even = 0, odd = 0;
    #pragma unroll
    for (int s = 0; s < NRG; s++) {
        uint x = cw[(size_t)s * (UNITS / 4) + w];
        even += x & 0x00FF00FFu;          // byte lanes 0,2 in u16 sub-lanes
        odd  += (x >> 8) & 0x00FF00FFu;   // byte lanes 1,3
    }
    const uint4 fd = ((const uint4*)fixdec)[w];
    const float4 dv = ((const float4*)duty)[w];
    const uint c[4] = {(even & 0xFFFFu) - fd.x, (odd & 0xFFFFu) - fd.y,
                       (even >> 16) - fd.z,     (odd >> 16) - fd.w};
    const float din[4] = {dv.x, dv.y, dv.z, dv.w};
    const float C1 = (float)(1.0 - 1.0 / 1000.0);
    const float C2 = (float)(1.0 / 1000.0);
    float o[4];
    #pragma unroll
    for (int j = 0; j < 4; j++) {
        float cur = (float)c[j] * (1.0f / 256.0f);   // exact
        o[j] = __fadd_rn(__fmul_rn(C1, din[j]), __fmul_rn(C2, cur));
    }
    f32x4 ov = {o[0], o[1], o[2], o[3]};
    *((f32x4*)out_duty + w) = ov;
}

extern "C" void kernel_launch(void* const* d_in, const int* in_sizes, int n_in,
                              void* d_out, int out_size, void* d_ws, size_t ws_size,
                              hipStream_t stream) {
    const float* inputs = (const float*)d_in[0];
    const float* duty   = (const float*)d_in[1];
    float* out      = (float*)d_out;
    float* out_duty = out + (size_t)BATCH * UNITS;

    char* ws = (char*)d_ws;
    float* boost  = (float*)(ws + 0);
    u16*  ghist   = (u16*)(ws + 524288);
    uint* candcnt = (uint*)(ws + 8912896);
    uint* b1_a    = (uint*)(ws + 8929280);
    uint* prior_a = (uint*)(ws + 8930304);
    u64*  candkv  = (u64*)(ws + 8931328);
    u8*   cnt8    = (u8*)(ws + 25708544);
    uint* fixdec  = (uint*)(ws + 29902848);

    boost_kernel<<<UNITS / 256, 256, 0, stream>>>(duty, boost, candcnt, fixdec);

    hist_kernel<<<dim3(NCHUNK, BATCH), 512, 0, stream>>>(inputs, boost, ghist);

    scan_kernel<<<BATCH, 512, 0, stream>>>(ghist, b1_a, prior_a);

    apply_kernel<<<dim3(UNITS / 4096, NRG), 512, 0, stream>>>(inputs, boost, b1_a, out,
                                                              cnt8, candcnt, candkv);

    fix_kernel<<<BATCH, 512, 0, stream>>>(candcnt, candkv, prior_a, out, fixdec);

    duty_kernel<<<UNITS / 2048, 512, 0, stream>>>(duty, cnt8, fixdec, out_duty);
}